// Round 10
// baseline (166.926 us; speedup 1.0000x reference)
//
#include <hip/hip_runtime.h>

// Problem: B=2, S=2048, D=512, H=8, dh=64.
// R13 = R12 with attn occupancy doubled (the remaining long pole):
//   attn was 512x512 = 4 waves/SIMD; per-step chain (MFMA->fma->exp2->fma)
//   is latency-bound and under-hidden. R13: 512 blocks x 1024 threads
//   (16 waves), each wave owns 128 t-rows (8 steps). 2 blocks/CU x 16 waves
//   = 8 waves/SIMD (2x TLP), SAME per-block Qh traffic (256KB) — unlike a
//   1024-block split which would double L2 reads. VGPR 60 <= 64 so
//   launch_bounds(1024,8) keeps full occupancy.
//   qgemm_k (512x256) unchanged from R12: XCD-aware h=bid>>6, m0=(bid&63)*64;
//     swizzled LDS staging, fp32->bf16 in regs, t[h] in B staging; epilogue
//     Qh bf16, nl = -0.125*log2e*||Q||, y = Q.t[h].
//   attn_k: out = sigmoid( softmax((2QQ^T - n_s - n_t)/8) @ y );
//     -n_s cancels in softmax; exp2 args bounded -> fp32-safe; bh=bid&15
//     XCD mapping; rotating-register 1-deep prefetch; zero barriers in loop.

typedef __attribute__((ext_vector_type(8))) short bf16x8;
typedef __attribute__((ext_vector_type(4))) float f32x4;

#if __has_builtin(__builtin_amdgcn_exp2f)
#define EXP2F(x) __builtin_amdgcn_exp2f(x)
#else
#define EXP2F(x) exp2f(x)
#endif

#define LOG2E 1.44269504088896341f
#define C025  (0.25f * LOG2E)
#define C0125 (0.125f * LOG2E)

__device__ inline unsigned int f2b(float f) {  // fp32 -> bf16 bits, RNE
    unsigned int u = __float_as_uint(f);
    return (u + 0x7fffu + ((u >> 16) & 1u)) >> 16;
}

// swizzled LDS tile: row stride 64 bf16 (128B), 16B chunk c at (c ^ (row&7))
#define SWZ(row, c) ((row) * 64 + (((c) ^ ((row) & 7)) * 8))

// ---- Qh = bf16(X @ Wq), nl, y; t computed in-block ----
__global__ __launch_bounds__(256) void qgemm_k(const float* __restrict__ X,
                                               const float* __restrict__ Wq,
                                               const float* __restrict__ Wv,
                                               unsigned short* __restrict__ Qh,
                                               float* __restrict__ nl_out,
                                               float* __restrict__ y_out) {
    __shared__ __align__(16) unsigned short As[64 * 64];
    __shared__ __align__(16) unsigned short Bs[64 * 64];
    __shared__ float tsh[256];
    int tid = threadIdx.x;
    int bid = blockIdx.x;
    int h = bid >> 6;                   // XCD-local: same-m0 blocks share bid%8
    int m0 = (bid & 63) * 64;
    int n0 = h * 64;
    int w = tid >> 6, lane = tid & 63;
    int tt = lane & 15, quad = lane >> 4;

    int arow = tid >> 3, achk = tid & 7;
    int bc = tid & 63, bjg = tid >> 6;

    const float* Xa0 = &X[(m0 + arow) * 512 + achk * 8];
    const float* Xa1 = Xa0 + 32 * 512;
    const float* Wb  = &Wq[n0 + bc];

    float4 a00, a01, a10, a11;
    float bv[16], wv[16];
    float tp = 0.f;
    f32x4 acc[4] = {{0.f,0.f,0.f,0.f},{0.f,0.f,0.f,0.f},
                    {0.f,0.f,0.f,0.f},{0.f,0.f,0.f,0.f}};

#define K1_LOADS(K0)                                                     \
    do {                                                                 \
        a00 = *(const float4*)&Xa0[(K0)];                                \
        a01 = *(const float4*)&Xa0[(K0) + 4];                            \
        a10 = *(const float4*)&Xa1[(K0)];                                \
        a11 = *(const float4*)&Xa1[(K0) + 4];                            \
        _Pragma("unroll")                                                \
        for (int i = 0; i < 8; ++i) {                                    \
            bv[i]     = Wb[((K0) + bjg * 8 + i) * 512];                  \
            bv[8 + i] = Wb[((K0) + (bjg + 4) * 8 + i) * 512];            \
            wv[i]     = Wv[(K0) + bjg * 8 + i];                          \
            wv[8 + i] = Wv[(K0) + (bjg + 4) * 8 + i];                    \
        }                                                                \
    } while (0)

    K1_LOADS(0);
    for (int k0 = 0; k0 < 512; k0 += 64) {
        __syncthreads();                 // prev compute done reading LDS
        uint4 o;
        o.x = f2b(a00.x) | (f2b(a00.y) << 16);
        o.y = f2b(a00.z) | (f2b(a00.w) << 16);
        o.z = f2b(a01.x) | (f2b(a01.y) << 16);
        o.w = f2b(a01.z) | (f2b(a01.w) << 16);
        *(uint4*)&As[SWZ(arow, achk)] = o;
        o.x = f2b(a10.x) | (f2b(a10.y) << 16);
        o.y = f2b(a10.z) | (f2b(a10.w) << 16);
        o.z = f2b(a11.x) | (f2b(a11.y) << 16);
        o.w = f2b(a11.z) | (f2b(a11.w) << 16);
        *(uint4*)&As[SWZ(arow + 32, achk)] = o;
        o.x = f2b(bv[0]) | (f2b(bv[1]) << 16);
        o.y = f2b(bv[2]) | (f2b(bv[3]) << 16);
        o.z = f2b(bv[4]) | (f2b(bv[5]) << 16);
        o.w = f2b(bv[6]) | (f2b(bv[7]) << 16);
        *(uint4*)&Bs[SWZ(bc, bjg)] = o;
        o.x = f2b(bv[8])  | (f2b(bv[9])  << 16);
        o.y = f2b(bv[10]) | (f2b(bv[11]) << 16);
        o.z = f2b(bv[12]) | (f2b(bv[13]) << 16);
        o.w = f2b(bv[14]) | (f2b(bv[15]) << 16);
        *(uint4*)&Bs[SWZ(bc, bjg + 4)] = o;
        #pragma unroll
        for (int i = 0; i < 16; ++i) tp = fmaf(bv[i], wv[i], tp);  // t[h] partial
        __syncthreads();
        if (k0 < 448) K1_LOADS(k0 + 64);  // next-tile loads overlap MFMAs below
        int ar = w * 16 + tt;
        bf16x8 fa0 = *(const bf16x8*)&As[SWZ(ar, quad)];
        bf16x8 fa1 = *(const bf16x8*)&As[SWZ(ar, quad + 4)];
        #pragma unroll
        for (int ct = 0; ct < 4; ++ct) {
            int br = ct * 16 + tt;
            bf16x8 fb0 = *(const bf16x8*)&Bs[SWZ(br, quad)];
            bf16x8 fb1 = *(const bf16x8*)&Bs[SWZ(br, quad + 4)];
            acc[ct] = __builtin_amdgcn_mfma_f32_16x16x32_bf16(fa0, fb0, acc[ct], 0, 0, 0);
            acc[ct] = __builtin_amdgcn_mfma_f32_16x16x32_bf16(fa1, fb1, acc[ct], 0, 0, 0);
        }
    }

    tsh[bjg * 64 + bc] = tp;
    __syncthreads();
    float tv[4];
    #pragma unroll
    for (int ct = 0; ct < 4; ++ct) {
        int c = ct * 16 + tt;
        tv[ct] = tsh[c] + tsh[64 + c] + tsh[128 + c] + tsh[192 + c];
    }

    float s2[4] = {0.f,0.f,0.f,0.f}, yp[4] = {0.f,0.f,0.f,0.f};
    #pragma unroll
    for (int ct = 0; ct < 4; ++ct)
        #pragma unroll
        for (int g = 0; g < 4; ++g) {
            float v = acc[ct][g];
            s2[g] = fmaf(v, v, s2[g]);
            yp[g] = fmaf(v, tv[ct], yp[g]);
            Qh[(m0 + w * 16 + quad * 4 + g) * 512 + n0 + ct * 16 + tt] =
                (unsigned short)f2b(v);
        }
    #pragma unroll
    for (int off = 1; off <= 8; off <<= 1)
        #pragma unroll
        for (int g = 0; g < 4; ++g) {
            s2[g] += __shfl_xor(s2[g], off);
            yp[g] += __shfl_xor(yp[g], off);
        }
    if (tt == 0) {
        int bb = m0 >> 11;
        #pragma unroll
        for (int g = 0; g < 4; ++g) {
            int row = m0 + w * 16 + quad * 4 + g;
            int idx = ((bb * 8 + h) << 11) + (row & 2047);
            nl_out[idx] = -C0125 * sqrtf(s2[g]);   // pre-scaled
            y_out[idx]  = yp[g];
        }
    }
}

// ---- attention: 64 q-rows/block; 16 waves own disjoint 128-row t-ranges ----
__global__ __launch_bounds__(1024, 8) void attn_k(const unsigned short* __restrict__ Qh,
                                                  const float* __restrict__ nl_in,
                                                  const float* __restrict__ y_in,
                                                  float* __restrict__ out) {
    __shared__ float redN[16][64];
    __shared__ float redD[16][64];
    int tid = threadIdx.x;
    int bid = blockIdx.x;
    int bh = bid & 15;                  // all 32 blocks of bh share bid%8 -> XCD
    int tile = bid >> 4;
    int s0 = tile * 64;
    int b = bh >> 3, h = bh & 7;
    const unsigned short* __restrict__ Qb = Qh + (size_t)(b * 2048) * 512 + h * 64;
    const float* __restrict__ nb = nl_in + bh * 2048;
    const float* __restrict__ yb = y_in + bh * 2048;
    int w = tid >> 6, lane = tid & 63;  // w in 0..15
    int tt = lane & 15, quad = lane >> 4;

    // A fragments for 4 s-tiles (held in registers for the whole kernel)
    bf16x8 fa0[4], fa1[4];
    #pragma unroll
    for (int tl = 0; tl < 4; ++tl) {
        const unsigned short* r = &Qb[(size_t)(s0 + tl * 16 + tt) * 512];
        fa0[tl] = *(const bf16x8*)&r[quad * 8];
        fa1[tl] = *(const bf16x8*)&r[32 + quad * 8];
    }
    f32x4 num[4] = {{0.f,0.f,0.f,0.f},{0.f,0.f,0.f,0.f},
                    {0.f,0.f,0.f,0.f},{0.f,0.f,0.f,0.f}};
    f32x4 den[4] = {{0.f,0.f,0.f,0.f},{0.f,0.f,0.f,0.f},
                    {0.f,0.f,0.f,0.f},{0.f,0.f,0.f,0.f}};

    // wave's t-range [w*128, w*128+128), rotating-register 1-deep prefetch
    const unsigned short* rT = &Qb[(size_t)(w * 128 + tt) * 512];
    bf16x8 fb0c = *(const bf16x8*)&rT[quad * 8];
    bf16x8 fb1c = *(const bf16x8*)&rT[32 + quad * 8];
    float tqc = nb[w * 128 + tt];
    float yvc = yb[w * 128 + tt];
    for (int st = 0; st < 8; ++st) {
        bf16x8 fb0n, fb1n;
        float tqn = 0.f, yvn = 0.f;
        if (st < 7) {
            int tnext = w * 128 + (st + 1) * 16 + tt;
            const unsigned short* rN = &Qb[(size_t)tnext * 512];
            fb0n = *(const bf16x8*)&rN[quad * 8];
            fb1n = *(const bf16x8*)&rN[32 + quad * 8];
            tqn = nb[tnext];
            yvn = yb[tnext];
        }
        #pragma unroll
        for (int tl = 0; tl < 4; ++tl) {
            f32x4 dot = {0.f, 0.f, 0.f, 0.f};
            dot = __builtin_amdgcn_mfma_f32_16x16x32_bf16(fa0[tl], fb0c, dot, 0, 0, 0);
            dot = __builtin_amdgcn_mfma_f32_16x16x32_bf16(fa1[tl], fb1c, dot, 0, 0, 0);
            #pragma unroll
            for (int g = 0; g < 4; ++g) {
                float arg = fmaf(C025, dot[g], tqc);
                float e = EXP2F(arg);
                num[tl][g] = fmaf(e, yvc, num[tl][g]);
                den[tl][g] += e;
            }
        }
        if (st < 7) { fb0c = fb0n; fb1c = fb1n; tqc = tqn; yvc = yvn; }
    }

    // reduce over 16 t-lanes, then across the 16 waves via LDS
    #pragma unroll
    for (int off = 1; off <= 8; off <<= 1)
        #pragma unroll
        for (int tl = 0; tl < 4; ++tl)
            #pragma unroll
            for (int g = 0; g < 4; ++g) {
                num[tl][g] += __shfl_xor(num[tl][g], off);
                den[tl][g] += __shfl_xor(den[tl][g], off);
            }
    if (tt == 0) {
        #pragma unroll
        for (int tl = 0; tl < 4; ++tl)
            #pragma unroll
            for (int g = 0; g < 4; ++g) {
                redN[w][tl * 16 + quad * 4 + g] = num[tl][g];
                redD[w][tl * 16 + quad * 4 + g] = den[tl][g];
            }
    }
    __syncthreads();
    if (tid < 64) {
        float xn = 0.f, xd = 0.f;
        #pragma unroll
        for (int ww = 0; ww < 16; ++ww) {
            xn += redN[ww][tid];
            xd += redD[ww][tid];
        }
        float x = xn / xd;
        out[bh * 2048 + s0 + tid] = 1.0f / (1.0f + EXP2F(-x * LOG2E));
    }
}

extern "C" void kernel_launch(void* const* d_in, const int* in_sizes, int n_in,
                              void* d_out, int out_size, void* d_ws, size_t ws_size,
                              hipStream_t stream) {
    const float* X  = (const float*)d_in[0];
    const float* Wq = (const float*)d_in[1];
    const float* Wv = (const float*)d_in[2];
    float* ws = (float*)d_ws;

    float* nl_ws = ws;                                      // 32768 floats
    float* y_ws  = ws + 32768;                              // 32768 floats
    unsigned short* Qh_ws = (unsigned short*)(ws + 65536);  // 2M bf16

    qgemm_k<<<512, 256, 0, stream>>>(X, Wq, Wv, Qh_ws, nl_ws, y_ws);
    attn_k<<<512, 1024, 0, stream>>>(Qh_ws, nl_ws, y_ws, (float*)d_out);
}

// Round 11
// 150.971 us; speedup vs baseline: 1.1057x; 1.1057x over previous
//
#include <hip/hip_runtime.h>

// Problem: B=2, S=2048, D=512, H=8, dh=64.
// R14 = R12 with TLP raised the register-safe way (R13's launch_bounds(1024,8)
// forced VGPR cap 64 < ~85 live -> 270MB scratch spill, 100us attn).
//   qgemm_k: 1024 blocks x 256 thr, 32-row tiles, launch_bounds(256,4)
//     (cap 128 >= ~90 live) -> 4 blocks/CU = 16 waves/CU (2x R12).
//     XCD map: h=bid>>7, m0=(bid&127)*32 -> same-X-panel blocks share bid%8.
//   attn_k: 1024 blocks x 512 thr, 32 q-rows/block (tl=2 -> fa 16 + num/den
//     16 + prefetch 16 ~= 65 live), launch_bounds(512,6) (cap ~85) ->
//     3 blocks/CU = 24 waves/CU = 6/SIMD (1.5x R12), zero spill.
//     XCD map: bh=bid&15 -> all 64 blocks of a bh on XCD bh%8; Qh slice
//     256KB L2-resident. Rotating 1-deep prefetch; zero barriers in loop.
// Math unchanged (verified R5-R12): nl = -0.125*log2e*||Q||, y = Q.t[h],
// out = sigmoid(softmax((2QQ^T - n_s - n_t)/8) @ y), -n_s cancels.

typedef __attribute__((ext_vector_type(8))) short bf16x8;
typedef __attribute__((ext_vector_type(4))) float f32x4;

#if __has_builtin(__builtin_amdgcn_exp2f)
#define EXP2F(x) __builtin_amdgcn_exp2f(x)
#else
#define EXP2F(x) exp2f(x)
#endif

#define LOG2E 1.44269504088896341f
#define C025  (0.25f * LOG2E)
#define C0125 (0.125f * LOG2E)

__device__ inline unsigned int f2b(float f) {  // fp32 -> bf16 bits, RNE
    unsigned int u = __float_as_uint(f);
    return (u + 0x7fffu + ((u >> 16) & 1u)) >> 16;
}

// swizzled LDS tile: row stride 64 bf16 (128B), 16B chunk c at (c ^ (row&7))
#define SWZ(row, c) ((row) * 64 + (((c) ^ ((row) & 7)) * 8))

// ---- Qh = bf16(X @ Wq), nl, y; t computed in-block. 32-row tiles ----
__global__ __launch_bounds__(256, 4) void qgemm_k(const float* __restrict__ X,
                                                  const float* __restrict__ Wq,
                                                  const float* __restrict__ Wv,
                                                  unsigned short* __restrict__ Qh,
                                                  float* __restrict__ nl_out,
                                                  float* __restrict__ y_out) {
    __shared__ __align__(16) unsigned short As[32 * 64];
    __shared__ __align__(16) unsigned short Bs[64 * 64];
    __shared__ float tsh[256];
    __shared__ float redS[2][32], redY[2][32];
    int tid = threadIdx.x;
    int bid = blockIdx.x;
    int h = bid >> 7;                   // 8 heads
    int m0 = (bid & 127) * 32;          // same-m0 blocks share bid%8 -> XCD
    int n0 = h * 64;
    int w = tid >> 6, lane = tid & 63;
    int tt = lane & 15, quad = lane >> 4;
    int rh = w & 1, ch = w >> 1;        // wave: row-half (16r), col-half (32c)

    int arow = tid >> 3, achk = tid & 7;   // A staging: 32 rows x 8 chunks
    int bc = tid & 63, bjg = tid >> 6;     // B staging: 64 cols x 8 chunks

    const float* Xa = &X[(m0 + arow) * 512 + achk * 8];
    const float* Wb = &Wq[n0 + bc];

    float4 a0v, a1v;
    float bv[16], wv[16];
    float tp = 0.f;
    f32x4 acc[2] = {{0.f,0.f,0.f,0.f},{0.f,0.f,0.f,0.f}};

#define K1_LOADS(K0)                                                     \
    do {                                                                 \
        a0v = *(const float4*)&Xa[(K0)];                                 \
        a1v = *(const float4*)&Xa[(K0) + 4];                             \
        _Pragma("unroll")                                                \
        for (int i = 0; i < 8; ++i) {                                    \
            bv[i]     = Wb[((K0) + bjg * 8 + i) * 512];                  \
            bv[8 + i] = Wb[((K0) + (bjg + 4) * 8 + i) * 512];            \
            wv[i]     = Wv[(K0) + bjg * 8 + i];                          \
            wv[8 + i] = Wv[(K0) + (bjg + 4) * 8 + i];                    \
        }                                                                \
    } while (0)

    K1_LOADS(0);
    for (int k0 = 0; k0 < 512; k0 += 64) {
        __syncthreads();                 // prev compute done reading LDS
        uint4 o;
        o.x = f2b(a0v.x) | (f2b(a0v.y) << 16);
        o.y = f2b(a0v.z) | (f2b(a0v.w) << 16);
        o.z = f2b(a1v.x) | (f2b(a1v.y) << 16);
        o.w = f2b(a1v.z) | (f2b(a1v.w) << 16);
        *(uint4*)&As[SWZ(arow, achk)] = o;
        o.x = f2b(bv[0]) | (f2b(bv[1]) << 16);
        o.y = f2b(bv[2]) | (f2b(bv[3]) << 16);
        o.z = f2b(bv[4]) | (f2b(bv[5]) << 16);
        o.w = f2b(bv[6]) | (f2b(bv[7]) << 16);
        *(uint4*)&Bs[SWZ(bc, bjg)] = o;
        o.x = f2b(bv[8])  | (f2b(bv[9])  << 16);
        o.y = f2b(bv[10]) | (f2b(bv[11]) << 16);
        o.z = f2b(bv[12]) | (f2b(bv[13]) << 16);
        o.w = f2b(bv[14]) | (f2b(bv[15]) << 16);
        *(uint4*)&Bs[SWZ(bc, bjg + 4)] = o;
        #pragma unroll
        for (int i = 0; i < 16; ++i) tp = fmaf(bv[i], wv[i], tp);  // t[h] partial
        __syncthreads();
        if (k0 < 448) K1_LOADS(k0 + 64);  // next-tile loads overlap MFMAs below
        int ar = rh * 16 + tt;
        bf16x8 fa0 = *(const bf16x8*)&As[SWZ(ar, quad)];
        bf16x8 fa1 = *(const bf16x8*)&As[SWZ(ar, quad + 4)];
        #pragma unroll
        for (int c = 0; c < 2; ++c) {
            int br = (ch * 2 + c) * 16 + tt;
            bf16x8 fb0 = *(const bf16x8*)&Bs[SWZ(br, quad)];
            bf16x8 fb1 = *(const bf16x8*)&Bs[SWZ(br, quad + 4)];
            acc[c] = __builtin_amdgcn_mfma_f32_16x16x32_bf16(fa0, fb0, acc[c], 0, 0, 0);
            acc[c] = __builtin_amdgcn_mfma_f32_16x16x32_bf16(fa1, fb1, acc[c], 0, 0, 0);
        }
    }

    // reduce t partials: 4 k-groups per column
    tsh[bjg * 64 + bc] = tp;
    __syncthreads();
    float tv[2];
    #pragma unroll
    for (int c = 0; c < 2; ++c) {
        int col = (ch * 2 + c) * 16 + tt;
        tv[c] = tsh[col] + tsh[64 + col] + tsh[128 + col] + tsh[192 + col];
    }

    float s2[4] = {0.f,0.f,0.f,0.f}, yp[4] = {0.f,0.f,0.f,0.f};
    #pragma unroll
    for (int c = 0; c < 2; ++c)
        #pragma unroll
        for (int g = 0; g < 4; ++g) {
            float v = acc[c][g];
            s2[g] = fmaf(v, v, s2[g]);
            yp[g] = fmaf(v, tv[c], yp[g]);
            Qh[(m0 + rh * 16 + quad * 4 + g) * 512 + n0 + (ch * 2 + c) * 16 + tt] =
                (unsigned short)f2b(v);
        }
    #pragma unroll
    for (int off = 1; off <= 8; off <<= 1)
        #pragma unroll
        for (int g = 0; g < 4; ++g) {
            s2[g] += __shfl_xor(s2[g], off);
            yp[g] += __shfl_xor(yp[g], off);
        }
    if (tt == 0) {
        #pragma unroll
        for (int g = 0; g < 4; ++g) {
            redS[ch][rh * 16 + quad * 4 + g] = s2[g];
            redY[ch][rh * 16 + quad * 4 + g] = yp[g];
        }
    }
    __syncthreads();
    if (tid < 32) {
        float s = redS[0][tid] + redS[1][tid];
        float y = redY[0][tid] + redY[1][tid];
        int row = m0 + tid;
        int bb = row >> 11;
        int idx = ((bb * 8 + h) << 11) + (row & 2047);
        nl_out[idx] = -C0125 * sqrtf(s);   // pre-scaled
        y_out[idx]  = y;
    }
}

// ---- attention: 32 q-rows/block; 8 waves own disjoint 256-row t-ranges ----
__global__ __launch_bounds__(512, 6) void attn_k(const unsigned short* __restrict__ Qh,
                                                 const float* __restrict__ nl_in,
                                                 const float* __restrict__ y_in,
                                                 float* __restrict__ out) {
    __shared__ float redN[8][32];
    __shared__ float redD[8][32];
    int tid = threadIdx.x;
    int bid = blockIdx.x;
    int bh = bid & 15;                  // all 64 blocks of bh on XCD bh%8
    int tile = bid >> 4;                // 64 tiles of 32 q-rows
    int s0 = tile * 32;
    int b = bh >> 3, h = bh & 7;
    const unsigned short* __restrict__ Qb = Qh + (size_t)(b * 2048) * 512 + h * 64;
    const float* __restrict__ nb = nl_in + bh * 2048;
    const float* __restrict__ yb = y_in + bh * 2048;
    int w = tid >> 6, lane = tid & 63;
    int tt = lane & 15, quad = lane >> 4;

    // A fragments for 2 s-tiles (in registers for the whole kernel)
    bf16x8 fa0[2], fa1[2];
    #pragma unroll
    for (int tl = 0; tl < 2; ++tl) {
        const unsigned short* r = &Qb[(size_t)(s0 + tl * 16 + tt) * 512];
        fa0[tl] = *(const bf16x8*)&r[quad * 8];
        fa1[tl] = *(const bf16x8*)&r[32 + quad * 8];
    }
    f32x4 num[2] = {{0.f,0.f,0.f,0.f},{0.f,0.f,0.f,0.f}};
    f32x4 den[2] = {{0.f,0.f,0.f,0.f},{0.f,0.f,0.f,0.f}};

    // wave's t-range [w*256, w*256+256), rotating-register 1-deep prefetch
    const unsigned short* rT = &Qb[(size_t)(w * 256 + tt) * 512];
    bf16x8 fb0c = *(const bf16x8*)&rT[quad * 8];
    bf16x8 fb1c = *(const bf16x8*)&rT[32 + quad * 8];
    float tqc = nb[w * 256 + tt];
    float yvc = yb[w * 256 + tt];
    for (int st = 0; st < 16; ++st) {
        bf16x8 fb0n, fb1n;
        float tqn = 0.f, yvn = 0.f;
        if (st < 15) {
            int tnext = w * 256 + (st + 1) * 16 + tt;
            const unsigned short* rN = &Qb[(size_t)tnext * 512];
            fb0n = *(const bf16x8*)&rN[quad * 8];
            fb1n = *(const bf16x8*)&rN[32 + quad * 8];
            tqn = nb[tnext];
            yvn = yb[tnext];
        }
        #pragma unroll
        for (int tl = 0; tl < 2; ++tl) {
            f32x4 dot = {0.f, 0.f, 0.f, 0.f};
            dot = __builtin_amdgcn_mfma_f32_16x16x32_bf16(fa0[tl], fb0c, dot, 0, 0, 0);
            dot = __builtin_amdgcn_mfma_f32_16x16x32_bf16(fa1[tl], fb1c, dot, 0, 0, 0);
            #pragma unroll
            for (int g = 0; g < 4; ++g) {
                float arg = fmaf(C025, dot[g], tqc);
                float e = EXP2F(arg);
                num[tl][g] = fmaf(e, yvc, num[tl][g]);
                den[tl][g] += e;
            }
        }
        if (st < 15) { fb0c = fb0n; fb1c = fb1n; tqc = tqn; yvc = yvn; }
    }

    // reduce over 16 t-lanes, then across the 8 waves via LDS
    #pragma unroll
    for (int off = 1; off <= 8; off <<= 1)
        #pragma unroll
        for (int tl = 0; tl < 2; ++tl)
            #pragma unroll
            for (int g = 0; g < 4; ++g) {
                num[tl][g] += __shfl_xor(num[tl][g], off);
                den[tl][g] += __shfl_xor(den[tl][g], off);
            }
    if (tt == 0) {
        #pragma unroll
        for (int tl = 0; tl < 2; ++tl)
            #pragma unroll
            for (int g = 0; g < 4; ++g) {
                redN[w][tl * 16 + quad * 4 + g] = num[tl][g];
                redD[w][tl * 16 + quad * 4 + g] = den[tl][g];
            }
    }
    __syncthreads();
    if (tid < 32) {
        float xn = 0.f, xd = 0.f;
        #pragma unroll
        for (int ww = 0; ww < 8; ++ww) {
            xn += redN[ww][tid];
            xd += redD[ww][tid];
        }
        float x = xn / xd;
        out[bh * 2048 + s0 + tid] = 1.0f / (1.0f + EXP2F(-x * LOG2E));
    }
}

extern "C" void kernel_launch(void* const* d_in, const int* in_sizes, int n_in,
                              void* d_out, int out_size, void* d_ws, size_t ws_size,
                              hipStream_t stream) {
    const float* X  = (const float*)d_in[0];
    const float* Wq = (const float*)d_in[1];
    const float* Wv = (const float*)d_in[2];
    float* ws = (float*)d_ws;

    float* nl_ws = ws;                                      // 32768 floats
    float* y_ws  = ws + 32768;                              // 32768 floats
    unsigned short* Qh_ws = (unsigned short*)(ws + 65536);  // 2M bf16

    qgemm_k<<<1024, 256, 0, stream>>>(X, Wq, Wv, Qh_ws, nl_ws, y_ws);
    attn_k<<<1024, 512, 0, stream>>>(Qh_ws, nl_ws, y_ws, (float*)d_out);
}

// Round 12
// 96.126 us; speedup vs baseline: 1.7365x; 1.5706x over previous
//
#include <hip/hip_runtime.h>

// Problem: B=2, S=2048, D=512, H=8, dh=64.
// R15 = exact revert to R12 (verified best, 96.97us window) + s_setprio(1)
// around the attn MFMA/exp cluster (guide-verified +4-7% on independent-wave
// attn; zero VGPR cost). R13/R14 lesson: launch_bounds minima that push the
// VGPR cap within ~15% of the live set spill catastrophically (190-270MB
// scratch). Only cap-128 configs verified safe -> keep (512,4)/(256).
//   qgemm_k (512x256): Q = X @ Wq via bf16 MFMA; fp32->bf16 in registers,
//     swizzled LDS staging, next-tile loads under MFMAs; t[h] = Wh^T Wv in
//     B staging. XCD map h=bid>>6, m0=(bid&63)*64. Epilogue: Qh bf16,
//     nl = -0.125*log2e*||Q||, y = Q.t[h].
//   attn_k (512x512): out = sigmoid( softmax((2QQ^T - n_s - n_t)/8) @ y ).
//     -n_s cancels; exp2 args bounded -> fp32-safe. XCD map bh=bid&15.
//     8 waves own disjoint 256-row t-ranges; rotating 1-deep prefetch;
//     zero barriers in main loop; setprio(1) around compute cluster.

typedef __attribute__((ext_vector_type(8))) short bf16x8;
typedef __attribute__((ext_vector_type(4))) float f32x4;

#if __has_builtin(__builtin_amdgcn_exp2f)
#define EXP2F(x) __builtin_amdgcn_exp2f(x)
#else
#define EXP2F(x) exp2f(x)
#endif

#define LOG2E 1.44269504088896341f
#define C025  (0.25f * LOG2E)
#define C0125 (0.125f * LOG2E)

__device__ inline unsigned int f2b(float f) {  // fp32 -> bf16 bits, RNE
    unsigned int u = __float_as_uint(f);
    return (u + 0x7fffu + ((u >> 16) & 1u)) >> 16;
}

// swizzled LDS tile: row stride 64 bf16 (128B), 16B chunk c at (c ^ (row&7))
#define SWZ(row, c) ((row) * 64 + (((c) ^ ((row) & 7)) * 8))

// ---- Qh = bf16(X @ Wq), nl, y; t computed in-block ----
__global__ __launch_bounds__(256) void qgemm_k(const float* __restrict__ X,
                                               const float* __restrict__ Wq,
                                               const float* __restrict__ Wv,
                                               unsigned short* __restrict__ Qh,
                                               float* __restrict__ nl_out,
                                               float* __restrict__ y_out) {
    __shared__ __align__(16) unsigned short As[64 * 64];
    __shared__ __align__(16) unsigned short Bs[64 * 64];
    __shared__ float tsh[256];
    int tid = threadIdx.x;
    int bid = blockIdx.x;
    int h = bid >> 6;                   // XCD-local: same-m0 blocks share bid%8
    int m0 = (bid & 63) * 64;
    int n0 = h * 64;
    int w = tid >> 6, lane = tid & 63;
    int tt = lane & 15, quad = lane >> 4;

    int arow = tid >> 3, achk = tid & 7;
    int bc = tid & 63, bjg = tid >> 6;

    const float* Xa0 = &X[(m0 + arow) * 512 + achk * 8];
    const float* Xa1 = Xa0 + 32 * 512;
    const float* Wb  = &Wq[n0 + bc];

    float4 a00, a01, a10, a11;
    float bv[16], wv[16];
    float tp = 0.f;
    f32x4 acc[4] = {{0.f,0.f,0.f,0.f},{0.f,0.f,0.f,0.f},
                    {0.f,0.f,0.f,0.f},{0.f,0.f,0.f,0.f}};

#define K1_LOADS(K0)                                                     \
    do {                                                                 \
        a00 = *(const float4*)&Xa0[(K0)];                                \
        a01 = *(const float4*)&Xa0[(K0) + 4];                            \
        a10 = *(const float4*)&Xa1[(K0)];                                \
        a11 = *(const float4*)&Xa1[(K0) + 4];                            \
        _Pragma("unroll")                                                \
        for (int i = 0; i < 8; ++i) {                                    \
            bv[i]     = Wb[((K0) + bjg * 8 + i) * 512];                  \
            bv[8 + i] = Wb[((K0) + (bjg + 4) * 8 + i) * 512];            \
            wv[i]     = Wv[(K0) + bjg * 8 + i];                          \
            wv[8 + i] = Wv[(K0) + (bjg + 4) * 8 + i];                    \
        }                                                                \
    } while (0)

    K1_LOADS(0);
    for (int k0 = 0; k0 < 512; k0 += 64) {
        __syncthreads();                 // prev compute done reading LDS
        uint4 o;
        o.x = f2b(a00.x) | (f2b(a00.y) << 16);
        o.y = f2b(a00.z) | (f2b(a00.w) << 16);
        o.z = f2b(a01.x) | (f2b(a01.y) << 16);
        o.w = f2b(a01.z) | (f2b(a01.w) << 16);
        *(uint4*)&As[SWZ(arow, achk)] = o;
        o.x = f2b(a10.x) | (f2b(a10.y) << 16);
        o.y = f2b(a10.z) | (f2b(a10.w) << 16);
        o.z = f2b(a11.x) | (f2b(a11.y) << 16);
        o.w = f2b(a11.z) | (f2b(a11.w) << 16);
        *(uint4*)&As[SWZ(arow + 32, achk)] = o;
        o.x = f2b(bv[0]) | (f2b(bv[1]) << 16);
        o.y = f2b(bv[2]) | (f2b(bv[3]) << 16);
        o.z = f2b(bv[4]) | (f2b(bv[5]) << 16);
        o.w = f2b(bv[6]) | (f2b(bv[7]) << 16);
        *(uint4*)&Bs[SWZ(bc, bjg)] = o;
        o.x = f2b(bv[8])  | (f2b(bv[9])  << 16);
        o.y = f2b(bv[10]) | (f2b(bv[11]) << 16);
        o.z = f2b(bv[12]) | (f2b(bv[13]) << 16);
        o.w = f2b(bv[14]) | (f2b(bv[15]) << 16);
        *(uint4*)&Bs[SWZ(bc, bjg + 4)] = o;
        #pragma unroll
        for (int i = 0; i < 16; ++i) tp = fmaf(bv[i], wv[i], tp);  // t[h] partial
        __syncthreads();
        if (k0 < 448) K1_LOADS(k0 + 64);  // next-tile loads overlap MFMAs below
        int ar = w * 16 + tt;
        bf16x8 fa0 = *(const bf16x8*)&As[SWZ(ar, quad)];
        bf16x8 fa1 = *(const bf16x8*)&As[SWZ(ar, quad + 4)];
        #pragma unroll
        for (int ct = 0; ct < 4; ++ct) {
            int br = ct * 16 + tt;
            bf16x8 fb0 = *(const bf16x8*)&Bs[SWZ(br, quad)];
            bf16x8 fb1 = *(const bf16x8*)&Bs[SWZ(br, quad + 4)];
            acc[ct] = __builtin_amdgcn_mfma_f32_16x16x32_bf16(fa0, fb0, acc[ct], 0, 0, 0);
            acc[ct] = __builtin_amdgcn_mfma_f32_16x16x32_bf16(fa1, fb1, acc[ct], 0, 0, 0);
        }
    }

    tsh[bjg * 64 + bc] = tp;
    __syncthreads();
    float tv[4];
    #pragma unroll
    for (int ct = 0; ct < 4; ++ct) {
        int c = ct * 16 + tt;
        tv[ct] = tsh[c] + tsh[64 + c] + tsh[128 + c] + tsh[192 + c];
    }

    float s2[4] = {0.f,0.f,0.f,0.f}, yp[4] = {0.f,0.f,0.f,0.f};
    #pragma unroll
    for (int ct = 0; ct < 4; ++ct)
        #pragma unroll
        for (int g = 0; g < 4; ++g) {
            float v = acc[ct][g];
            s2[g] = fmaf(v, v, s2[g]);
            yp[g] = fmaf(v, tv[ct], yp[g]);
            Qh[(m0 + w * 16 + quad * 4 + g) * 512 + n0 + ct * 16 + tt] =
                (unsigned short)f2b(v);
        }
    #pragma unroll
    for (int off = 1; off <= 8; off <<= 1)
        #pragma unroll
        for (int g = 0; g < 4; ++g) {
            s2[g] += __shfl_xor(s2[g], off);
            yp[g] += __shfl_xor(yp[g], off);
        }
    if (tt == 0) {
        int bb = m0 >> 11;
        #pragma unroll
        for (int g = 0; g < 4; ++g) {
            int row = m0 + w * 16 + quad * 4 + g;
            int idx = ((bb * 8 + h) << 11) + (row & 2047);
            nl_out[idx] = -C0125 * sqrtf(s2[g]);   // pre-scaled
            y_out[idx]  = yp[g];
        }
    }
}

// ---- attention: 64 q-rows/block; 8 waves own disjoint 256-row t-ranges ----
__global__ __launch_bounds__(512, 4) void attn_k(const unsigned short* __restrict__ Qh,
                                                 const float* __restrict__ nl_in,
                                                 const float* __restrict__ y_in,
                                                 float* __restrict__ out) {
    __shared__ float redN[8][64];
    __shared__ float redD[8][64];
    int tid = threadIdx.x;
    int bid = blockIdx.x;
    int bh = bid & 15;                  // all 32 blocks of bh share bid%8 -> XCD
    int tile = bid >> 4;
    int s0 = tile * 64;
    int b = bh >> 3, h = bh & 7;
    const unsigned short* __restrict__ Qb = Qh + (size_t)(b * 2048) * 512 + h * 64;
    const float* __restrict__ nb = nl_in + bh * 2048;
    const float* __restrict__ yb = y_in + bh * 2048;
    int w = tid >> 6, lane = tid & 63;
    int tt = lane & 15, quad = lane >> 4;

    // A fragments for 4 s-tiles (held in registers for the whole kernel)
    bf16x8 fa0[4], fa1[4];
    #pragma unroll
    for (int tl = 0; tl < 4; ++tl) {
        const unsigned short* r = &Qb[(size_t)(s0 + tl * 16 + tt) * 512];
        fa0[tl] = *(const bf16x8*)&r[quad * 8];
        fa1[tl] = *(const bf16x8*)&r[32 + quad * 8];
    }
    f32x4 num[4] = {{0.f,0.f,0.f,0.f},{0.f,0.f,0.f,0.f},
                    {0.f,0.f,0.f,0.f},{0.f,0.f,0.f,0.f}};
    f32x4 den[4] = {{0.f,0.f,0.f,0.f},{0.f,0.f,0.f,0.f},
                    {0.f,0.f,0.f,0.f},{0.f,0.f,0.f,0.f}};

    // wave's t-range [w*256, w*256+256), rotating-register 1-deep prefetch
    const unsigned short* rT = &Qb[(size_t)(w * 256 + tt) * 512];
    bf16x8 fb0c = *(const bf16x8*)&rT[quad * 8];
    bf16x8 fb1c = *(const bf16x8*)&rT[32 + quad * 8];
    float tqc = nb[w * 256 + tt];
    float yvc = yb[w * 256 + tt];
    for (int st = 0; st < 16; ++st) {
        bf16x8 fb0n, fb1n;
        float tqn = 0.f, yvn = 0.f;
        if (st < 15) {
            int tnext = w * 256 + (st + 1) * 16 + tt;
            const unsigned short* rN = &Qb[(size_t)tnext * 512];
            fb0n = *(const bf16x8*)&rN[quad * 8];
            fb1n = *(const bf16x8*)&rN[32 + quad * 8];
            tqn = nb[tnext];
            yvn = yb[tnext];
        }
        // boost this wave while it owns the MFMA+TRANS pipes (independent
        // waves, no barrier -> scheduler has real arbitration to do)
        __builtin_amdgcn_s_setprio(1);
        #pragma unroll
        for (int tl = 0; tl < 4; ++tl) {
            f32x4 dot = {0.f, 0.f, 0.f, 0.f};
            dot = __builtin_amdgcn_mfma_f32_16x16x32_bf16(fa0[tl], fb0c, dot, 0, 0, 0);
            dot = __builtin_amdgcn_mfma_f32_16x16x32_bf16(fa1[tl], fb1c, dot, 0, 0, 0);
            #pragma unroll
            for (int g = 0; g < 4; ++g) {
                float arg = fmaf(C025, dot[g], tqc);
                float e = EXP2F(arg);
                num[tl][g] = fmaf(e, yvc, num[tl][g]);
                den[tl][g] += e;
            }
        }
        __builtin_amdgcn_s_setprio(0);
        if (st < 15) { fb0c = fb0n; fb1c = fb1n; tqc = tqn; yvc = yvn; }
    }

    // reduce over 16 t-lanes, then across the 8 waves via LDS
    #pragma unroll
    for (int off = 1; off <= 8; off <<= 1)
        #pragma unroll
        for (int tl = 0; tl < 4; ++tl)
            #pragma unroll
            for (int g = 0; g < 4; ++g) {
                num[tl][g] += __shfl_xor(num[tl][g], off);
                den[tl][g] += __shfl_xor(den[tl][g], off);
            }
    if (tt == 0) {
        #pragma unroll
        for (int tl = 0; tl < 4; ++tl)
            #pragma unroll
            for (int g = 0; g < 4; ++g) {
                redN[w][tl * 16 + quad * 4 + g] = num[tl][g];
                redD[w][tl * 16 + quad * 4 + g] = den[tl][g];
            }
    }
    __syncthreads();
    if (tid < 64) {
        float xn = 0.f, xd = 0.f;
        #pragma unroll
        for (int ww = 0; ww < 8; ++ww) {
            xn += redN[ww][tid];
            xd += redD[ww][tid];
        }
        float x = xn / xd;
        out[bh * 2048 + s0 + tid] = 1.0f / (1.0f + EXP2F(-x * LOG2E));
    }
}

extern "C" void kernel_launch(void* const* d_in, const int* in_sizes, int n_in,
                              void* d_out, int out_size, void* d_ws, size_t ws_size,
                              hipStream_t stream) {
    const float* X  = (const float*)d_in[0];
    const float* Wq = (const float*)d_in[1];
    const float* Wv = (const float*)d_in[2];
    float* ws = (float*)d_ws;

    float* nl_ws = ws;                                      // 32768 floats
    float* y_ws  = ws + 32768;                              // 32768 floats
    unsigned short* Qh_ws = (unsigned short*)(ws + 65536);  // 2M bf16

    qgemm_k<<<512, 256, 0, stream>>>(X, Wq, Wv, Qh_ws, nl_ws, y_ws);
    attn_k<<<512, 512, 0, stream>>>(Qh_ws, nl_ws, y_ws, (float*)d_out);
}